// Round 2
// baseline (249.460 us; speedup 1.0000x reference)
//
#include <hip/hip_runtime.h>
#include <hip/hip_bf16.h>

#define NG     2048
#define HW     128
#define NPIX   (HW*HW)
#define SEG    16
#define CHUNK  (NG/SEG)   // 128
#define NEARZ  0.3f
#define GEPS   1e-4f

// ---- scratch in static device globals (no d_ws dependence, fully
// rewritten every call so graph replay is deterministic) -------------------
__device__ float  g_r[NG];
__device__ float4 g_ga_u[NG];
__device__ float4 g_gb_u[NG];
__device__ float  g_cb_u[NG];
__device__ float4 g_ga_s[NG];
__device__ float4 g_gb_s[NG];
__device__ float  g_cb_s[NG];

__device__ __forceinline__ float sigm(float x) { return 1.0f / (1.0f + __expf(-x)); }

// runtime dtype discriminator: rot[0][1] == 0.0 exactly.
//  bf16 buffer: 16-bit word #1 is rot[1] = 0x0000.
//  f32  buffer: 16-bit word #1 is the HIGH half of rot[0]=cos(0.05) = 0x3F7F.
__device__ __forceinline__ bool detect_f32(const void* rot) {
    return ((const unsigned short*)rot)[1] != 0;
}

// dtype-flexible scalar load
__device__ __forceinline__ float ld(const void* p, int idx, bool f32) {
    if (f32) return ((const float*)p)[idx];
    return __bfloat162float(((const __hip_bfloat16*)p)[idx]);
}

// ---------------------------------------------------------------------------
// Kernel 1: per-gaussian projection + 2D covariance inverse + activations
// ---------------------------------------------------------------------------
__global__ __launch_bounds__(256)
void preprocess_kernel(const void* __restrict__ pos,
                       const void* __restrict__ rgb,
                       const void* __restrict__ opa,
                       const void* __restrict__ quat,
                       const void* __restrict__ scale,
                       const void* __restrict__ rot,
                       const void* __restrict__ tran)
{
    int i = blockIdx.x * blockDim.x + threadIdx.x;
    if (i >= NG) return;
    bool f32 = detect_f32(rot);

    float R[9], T3[3];
    #pragma unroll
    for (int k = 0; k < 9; k++) R[k] = ld(rot, k, f32);
    #pragma unroll
    for (int k = 0; k < 3; k++) T3[k] = ld(tran, k, f32);

    float p0 = ld(pos, i*3+0, f32), p1 = ld(pos, i*3+1, f32), p2 = ld(pos, i*3+2, f32);
    // pos_cam = pos @ rot^T + tran
    float x = R[0]*p0 + R[1]*p1 + R[2]*p2 + T3[0];
    float y = R[3]*p0 + R[4]*p1 + R[5]*p2 + T3[1];
    float z = R[6]*p0 + R[7]*p1 + R[8]*p2 + T3[2];
    float r = sqrtf(x*x + y*y + z*z);
    float iz = 1.0f / z;
    float u = x * iz, v = y * iz;

    // quaternion (w,x,y,z) -> rotation matrix
    float qw = ld(quat, i*4+0, f32), qx = ld(quat, i*4+1, f32);
    float qy = ld(quat, i*4+2, f32), qz = ld(quat, i*4+3, f32);
    float qn = 1.0f / sqrtf(qw*qw + qx*qx + qy*qy + qz*qz);
    qw *= qn; qx *= qn; qy *= qn; qz *= qn;
    float Rm[3][3];
    Rm[0][0] = 1.0f - 2.0f*(qy*qy + qz*qz);
    Rm[0][1] = 2.0f*(qx*qy - qw*qz);
    Rm[0][2] = 2.0f*(qx*qz + qw*qy);
    Rm[1][0] = 2.0f*(qx*qy + qw*qz);
    Rm[1][1] = 1.0f - 2.0f*(qx*qx + qz*qz);
    Rm[1][2] = 2.0f*(qy*qz - qw*qx);
    Rm[2][0] = 2.0f*(qx*qz - qw*qy);
    Rm[2][1] = 2.0f*(qy*qz + qw*qx);
    Rm[2][2] = 1.0f - 2.0f*(qx*qx + qy*qy);

    float s[3];
    #pragma unroll
    for (int k = 0; k < 3; k++) s[k] = fabsf(ld(scale, i*3+k, f32)) + 1e-4f;

    float RS[3][3];
    #pragma unroll
    for (int a = 0; a < 3; a++)
        #pragma unroll
        for (int b = 0; b < 3; b++) RS[a][b] = Rm[a][b] * s[b];
    float C3[3][3];
    #pragma unroll
    for (int a = 0; a < 3; a++)
        #pragma unroll
        for (int b = 0; b < 3; b++)
            C3[a][b] = RS[a][0]*RS[b][0] + RS[a][1]*RS[b][1] + RS[a][2]*RS[b][2];

    // JW rows 0,1 (row 2 only feeds discarded cov2d entries)
    float nx = -x * iz * iz, ny = -y * iz * iz;
    float jw0[3], jw1[3];
    #pragma unroll
    for (int k = 0; k < 3; k++) {
        jw0[k] = iz * R[0*3+k] + nx * R[2*3+k];
        jw1[k] = iz * R[1*3+k] + ny * R[2*3+k];
    }
    float t0[3], t1[3];
    #pragma unroll
    for (int j = 0; j < 3; j++) {
        t0[j] = C3[j][0]*jw0[0] + C3[j][1]*jw0[1] + C3[j][2]*jw0[2];
        t1[j] = C3[j][0]*jw1[0] + C3[j][1]*jw1[1] + C3[j][2]*jw1[2];
    }
    float a = jw0[0]*t0[0] + jw0[1]*t0[1] + jw0[2]*t0[2] + GEPS;
    float b = jw0[0]*t1[0] + jw0[1]*t1[1] + jw0[2]*t1[2];
    float c = jw1[0]*t1[0] + jw1[1]*t1[1] + jw1[2]*t1[2] + GEPS;
    float idet = 1.0f / (a*c - b*b);
    float ia = c * idet, ib = -b * idet, ic = a * idet;

    float om = (z > NEARZ) ? sigm(ld(opa, i, f32)) : 0.0f;  // near-mask folded
    float cr = sigm(ld(rgb, i*3+0, f32));
    float cg = sigm(ld(rgb, i*3+1, f32));
    float cb = sigm(ld(rgb, i*3+2, f32));

    g_r[i]    = r;
    g_ga_u[i] = make_float4(u, v, ia, ib);
    g_gb_u[i] = make_float4(ic, om, cr, cg);
    g_cb_u[i] = cb;
}

// ---------------------------------------------------------------------------
// Kernel 2: stable rank sort by r (matches jnp.argsort stability)
// ---------------------------------------------------------------------------
__global__ __launch_bounds__(256)
void sort_kernel()
{
    __shared__ float rs[NG];
    int t = threadIdx.x;
    int i = blockIdx.x * blockDim.x + t;
    for (int k = t; k < NG; k += blockDim.x) rs[k] = g_r[k];
    __syncthreads();

    float ri = rs[i];
    int rank = 0;
    #pragma unroll 8
    for (int j = 0; j < NG; j++) {
        float rj = rs[j];
        rank += (rj < ri) || (rj == ri && j < i);
    }
    g_ga_s[rank] = g_ga_u[i];
    g_gb_s[rank] = g_gb_u[i];
    g_cb_s[rank] = g_cb_u[i];
}

// ---------------------------------------------------------------------------
// Kernel 3: rasterize. 16 lanes/pixel, each composites a 128-gaussian
// segment; ordered xor-shuffle combine (T1,C1)o(T2,C2)=(T1T2, C1+T1*C2)
// ---------------------------------------------------------------------------
__global__ __launch_bounds__(256)
void raster_kernel(void* __restrict__ out, const void* __restrict__ rot)
{
    int gt  = blockIdx.x * blockDim.x + threadIdx.x;
    int seg = gt & (SEG - 1);
    int pix = gt >> 4;
    int row = pix >> 7;
    int col = pix & 127;
    float pxf = (col - 63.5f) * (1.0f / 128.0f);
    float pyf = (row - 63.5f) * (1.0f / 128.0f);

    float T = 1.0f, Cr = 0.0f, Cg = 0.0f, Cb = 0.0f;
    int base = seg * CHUNK;
    for (int k = 0; k < CHUNK; k++) {
        float4 a4 = g_ga_s[base + k];
        float4 b4 = g_gb_s[base + k];
        float  cb = g_cb_s[base + k];
        float dx = pxf - a4.x;
        float dy = pyf - a4.y;
        float power = -0.5f * (a4.z*dx*dx + 2.0f*a4.w*dx*dy + b4.x*dy*dy);
        power = fminf(power, 0.0f);            // mathematically a no-op; kills any inf
        float alpha = fminf(b4.y * __expf(power), 0.99f);
        float w = T * alpha;
        Cr = fmaf(w, b4.z, Cr);
        Cg = fmaf(w, b4.w, Cg);
        Cb = fmaf(w, cb, Cb);
        T *= (1.0f - alpha);
    }

    #pragma unroll
    for (int d = 1; d < SEG; d <<= 1) {
        float oT  = __shfl_xor(T,  d);
        float oCr = __shfl_xor(Cr, d);
        float oCg = __shfl_xor(Cg, d);
        float oCb = __shfl_xor(Cb, d);
        bool up = (seg & d) != 0;
        float nCr = up ? fmaf(oT, Cr, oCr) : fmaf(T, oCr, Cr);
        float nCg = up ? fmaf(oT, Cg, oCg) : fmaf(T, oCg, Cg);
        float nCb = up ? fmaf(oT, Cb, oCb) : fmaf(T, oCb, Cb);
        T = T * oT; Cr = nCr; Cg = nCg; Cb = nCb;
    }

    if (seg == 0) {
        bool f32 = detect_f32(rot);
        if (f32) {
            float* o = (float*)out;
            o[pix*3 + 0] = Cr; o[pix*3 + 1] = Cg; o[pix*3 + 2] = Cb;
        } else {
            __hip_bfloat16* o = (__hip_bfloat16*)out;
            o[pix*3 + 0] = __float2bfloat16(Cr);
            o[pix*3 + 1] = __float2bfloat16(Cg);
            o[pix*3 + 2] = __float2bfloat16(Cb);
        }
    }
}

// ---------------------------------------------------------------------------
extern "C" void kernel_launch(void* const* d_in, const int* in_sizes, int n_in,
                              void* d_out, int out_size, void* d_ws, size_t ws_size,
                              hipStream_t stream)
{
    const void* pos   = d_in[0];
    const void* rgb   = d_in[1];
    const void* opa   = d_in[2];
    const void* quat  = d_in[3];
    const void* scale = d_in[4];
    const void* rot   = d_in[5];
    const void* tran  = d_in[6];

    preprocess_kernel<<<NG/256, 256, 0, stream>>>(pos, rgb, opa, quat, scale, rot, tran);
    sort_kernel<<<NG/256, 256, 0, stream>>>();
    raster_kernel<<<(NPIX*SEG)/256, 256, 0, stream>>>(d_out, rot);
}

// Round 3
// 98.959 us; speedup vs baseline: 2.5208x; 2.5208x over previous
//
#include <hip/hip_runtime.h>
#include <hip/hip_bf16.h>

#define NG     2048
#define HW     128
#define NPIX   (HW*HW)
#define SEG    16
#define CHUNK  (NG/SEG)   // 128
#define NEARZ  0.3f
#define GEPS   1e-4f
#define LOG2E  1.4426950408889634f

// ---- scratch in static device globals (rewritten every call) -------------
__device__ float  g_r[NG];
__device__ float4 g_ga_u[NG];   // u, v, A, B   (A,B,C have -0.5*log2e folded)
__device__ float4 g_gb_u[NG];   // C, opa_masked, cr, cg
__device__ float  g_cb_u[NG];
__device__ float4 g_ga_s[NG];
__device__ float4 g_gb_s[NG];
__device__ float  g_cb_s[NG];

__device__ __forceinline__ float sigm(float x) { return 1.0f / (1.0f + __expf(-x)); }

// dtype discriminator (proven f32 in R2, kept for safety):
// rot[0][1]==0.0 exactly -> 16-bit word #1 is 0x0000 for bf16, 0x3F7F for f32.
__device__ __forceinline__ bool detect_f32(const void* rot) {
    return ((const unsigned short*)rot)[1] != 0;
}
__device__ __forceinline__ float ld(const void* p, int idx, bool f32) {
    if (f32) return ((const float*)p)[idx];
    return __bfloat162float(((const __hip_bfloat16*)p)[idx]);
}

// ---------------------------------------------------------------------------
// Kernel 1: per-gaussian projection + conic + activations (2048 threads)
// ---------------------------------------------------------------------------
__global__ __launch_bounds__(256)
void preprocess_kernel(const void* __restrict__ pos,
                       const void* __restrict__ rgb,
                       const void* __restrict__ opa,
                       const void* __restrict__ quat,
                       const void* __restrict__ scale,
                       const void* __restrict__ rot,
                       const void* __restrict__ tran)
{
    int i = blockIdx.x * blockDim.x + threadIdx.x;
    if (i >= NG) return;
    bool f32 = detect_f32(rot);

    float R[9], T3[3];
    #pragma unroll
    for (int k = 0; k < 9; k++) R[k] = ld(rot, k, f32);
    #pragma unroll
    for (int k = 0; k < 3; k++) T3[k] = ld(tran, k, f32);

    float p0 = ld(pos, i*3+0, f32), p1 = ld(pos, i*3+1, f32), p2 = ld(pos, i*3+2, f32);
    float x = R[0]*p0 + R[1]*p1 + R[2]*p2 + T3[0];
    float y = R[3]*p0 + R[4]*p1 + R[5]*p2 + T3[1];
    float z = R[6]*p0 + R[7]*p1 + R[8]*p2 + T3[2];
    float r = sqrtf(x*x + y*y + z*z);
    float iz = 1.0f / z;
    float u = x * iz, v = y * iz;

    float qw = ld(quat, i*4+0, f32), qx = ld(quat, i*4+1, f32);
    float qy = ld(quat, i*4+2, f32), qz = ld(quat, i*4+3, f32);
    float qn = 1.0f / sqrtf(qw*qw + qx*qx + qy*qy + qz*qz);
    qw *= qn; qx *= qn; qy *= qn; qz *= qn;
    float Rm[3][3];
    Rm[0][0] = 1.0f - 2.0f*(qy*qy + qz*qz);
    Rm[0][1] = 2.0f*(qx*qy - qw*qz);
    Rm[0][2] = 2.0f*(qx*qz + qw*qy);
    Rm[1][0] = 2.0f*(qx*qy + qw*qz);
    Rm[1][1] = 1.0f - 2.0f*(qx*qx + qz*qz);
    Rm[1][2] = 2.0f*(qy*qz - qw*qx);
    Rm[2][0] = 2.0f*(qx*qz - qw*qy);
    Rm[2][1] = 2.0f*(qy*qz + qw*qx);
    Rm[2][2] = 1.0f - 2.0f*(qx*qx + qy*qy);

    float s[3];
    #pragma unroll
    for (int k = 0; k < 3; k++) s[k] = fabsf(ld(scale, i*3+k, f32)) + 1e-4f;

    float RS[3][3];
    #pragma unroll
    for (int a = 0; a < 3; a++)
        #pragma unroll
        for (int b = 0; b < 3; b++) RS[a][b] = Rm[a][b] * s[b];
    float C3[3][3];
    #pragma unroll
    for (int a = 0; a < 3; a++)
        #pragma unroll
        for (int b = 0; b < 3; b++)
            C3[a][b] = RS[a][0]*RS[b][0] + RS[a][1]*RS[b][1] + RS[a][2]*RS[b][2];

    float nx = -x * iz * iz, ny = -y * iz * iz;
    float jw0[3], jw1[3];
    #pragma unroll
    for (int k = 0; k < 3; k++) {
        jw0[k] = iz * R[0*3+k] + nx * R[2*3+k];
        jw1[k] = iz * R[1*3+k] + ny * R[2*3+k];
    }
    float t0[3], t1[3];
    #pragma unroll
    for (int j = 0; j < 3; j++) {
        t0[j] = C3[j][0]*jw0[0] + C3[j][1]*jw0[1] + C3[j][2]*jw0[2];
        t1[j] = C3[j][0]*jw1[0] + C3[j][1]*jw1[1] + C3[j][2]*jw1[2];
    }
    float a = jw0[0]*t0[0] + jw0[1]*t0[1] + jw0[2]*t0[2] + GEPS;
    float b = jw0[0]*t1[0] + jw0[1]*t1[1] + jw0[2]*t1[2];
    float c = jw1[0]*t1[0] + jw1[1]*t1[1] + jw1[2]*t1[2] + GEPS;
    float idet = 1.0f / (a*c - b*b);
    // conic with exp2 conversion + the -0.5 factor folded in
    float Af = -0.5f * LOG2E * (c * idet);
    float Bf = -LOG2E * (-b * idet);
    float Cf = -0.5f * LOG2E * (a * idet);

    float om = (z > NEARZ) ? sigm(ld(opa, i, f32)) : 0.0f;
    float cr = sigm(ld(rgb, i*3+0, f32));
    float cg = sigm(ld(rgb, i*3+1, f32));
    float cb = sigm(ld(rgb, i*3+2, f32));

    g_r[i]    = r;
    g_ga_u[i] = make_float4(u, v, Af, Bf);
    g_gb_u[i] = make_float4(Cf, om, cr, cg);
    g_cb_u[i] = cb;
}

// ---------------------------------------------------------------------------
// Kernel 2: stable rank sort, 16 lanes per gaussian (32768 threads)
// ---------------------------------------------------------------------------
__global__ __launch_bounds__(256)
void sort_kernel()
{
    __shared__ float rs[NG];
    int tid = threadIdx.x;
    for (int k = tid; k < NG; k += 256) rs[k] = g_r[k];
    __syncthreads();

    int g      = (blockIdx.x * 256 + tid) >> 4;   // gaussian id
    int lane16 = tid & 15;                        // slice within gaussian
    float ri = rs[g];

    int rank = 0;
    int jbase = lane16 * (NG / 16);               // 128-key slice
    #pragma unroll 4
    for (int jj = 0; jj < NG / 16; jj++) {
        int j = jbase + ((jj + 2 * lane16) & (NG / 16 - 1)); // bank-swizzle
        float rj = rs[j];
        rank += (rj < ri) || (rj == ri && j < g);
    }
    #pragma unroll
    for (int d = 1; d < 16; d <<= 1) rank += __shfl_xor(rank, d);

    if (lane16 == 0) {
        g_ga_s[rank] = g_ga_u[g];
        g_gb_s[rank] = g_gb_u[g];
        g_cb_s[rank] = g_cb_u[g];
    }
}

// ---------------------------------------------------------------------------
// Kernel 3: rasterize. Block = 16 waves; wave w composites segment w for
// 64 pixels (pixel = lane). Gaussian loads are wave-uniform -> SMEM path.
// Cross-segment combine via LDS, done by wave 0.
// ---------------------------------------------------------------------------
__global__ __launch_bounds__(1024)
void raster_kernel(void* __restrict__ out, const void* __restrict__ rot)
{
    __shared__ float4 comb[SEG * 64];   // (T, Cr, Cg, Cb) per (seg, pixel)

    int tid  = threadIdx.x;
    int lane = tid & 63;
    int w    = __builtin_amdgcn_readfirstlane(tid >> 6);  // wave-uniform seg

    int pix = blockIdx.x * 64 + lane;
    int row = pix >> 7;
    int col = pix & 127;
    float pxf = (col - 63.5f) * (1.0f / 128.0f);
    float pyf = (row - 63.5f) * (1.0f / 128.0f);

    float T = 1.0f, Cr = 0.0f, Cg = 0.0f, Cb = 0.0f;
    int base = w * CHUNK;
    #pragma unroll 4
    for (int k = 0; k < CHUNK; k++) {
        float4 a4 = g_ga_s[base + k];   // wave-uniform address
        float4 b4 = g_gb_s[base + k];
        float  cb = g_cb_s[base + k];
        float dx = pxf - a4.x;
        float dy = pyf - a4.y;
        float p  = (a4.z * dx + a4.w * dy) * dx;     // A dx^2 + B dx dy
        p = fmaf(b4.x * dy, dy, p);                  // + C dy^2  (log2-domain)
        p = fminf(p, 0.0f);
        float alpha = fminf(b4.y * __builtin_amdgcn_exp2f(p), 0.99f);
        float wgt = T * alpha;
        Cr = fmaf(wgt, b4.z, Cr);
        Cg = fmaf(wgt, b4.w, Cg);
        Cb = fmaf(wgt, cb, Cb);
        T *= (1.0f - alpha);
    }

    comb[w * 64 + lane] = make_float4(T, Cr, Cg, Cb);
    __syncthreads();

    if (tid < 64) {
        float Ta = 1.0f, Ra = 0.0f, Ga = 0.0f, Ba = 0.0f;
        #pragma unroll
        for (int s = 0; s < SEG; s++) {
            float4 c4 = comb[s * 64 + lane];
            Ra = fmaf(Ta, c4.y, Ra);
            Ga = fmaf(Ta, c4.z, Ga);
            Ba = fmaf(Ta, c4.w, Ba);
            Ta *= c4.x;
        }
        bool f32 = detect_f32(rot);
        if (f32) {
            float* o = (float*)out;
            o[pix*3 + 0] = Ra; o[pix*3 + 1] = Ga; o[pix*3 + 2] = Ba;
        } else {
            __hip_bfloat16* o = (__hip_bfloat16*)out;
            o[pix*3 + 0] = __float2bfloat16(Ra);
            o[pix*3 + 1] = __float2bfloat16(Ga);
            o[pix*3 + 2] = __float2bfloat16(Ba);
        }
    }
}

// ---------------------------------------------------------------------------
extern "C" void kernel_launch(void* const* d_in, const int* in_sizes, int n_in,
                              void* d_out, int out_size, void* d_ws, size_t ws_size,
                              hipStream_t stream)
{
    const void* pos   = d_in[0];
    const void* rgb   = d_in[1];
    const void* opa   = d_in[2];
    const void* quat  = d_in[3];
    const void* scale = d_in[4];
    const void* rot   = d_in[5];
    const void* tran  = d_in[6];

    preprocess_kernel<<<NG/256, 256, 0, stream>>>(pos, rgb, opa, quat, scale, rot, tran);
    sort_kernel<<<(NG*16)/256, 256, 0, stream>>>();
    raster_kernel<<<NPIX/64, 1024, 0, stream>>>(d_out, rot);
}

// Round 4
// 97.192 us; speedup vs baseline: 2.5667x; 1.0182x over previous
//
#include <hip/hip_runtime.h>
#include <hip/hip_bf16.h>

#define NG     2048
#define HW     128
#define NPIX   (HW*HW)
#define SEG    16
#define CHUNK  (NG/SEG)   // 128
#define NEARZ  0.3f
#define GEPS   1e-4f
#define LOG2E  1.4426950408889634f

// ---- sorted gaussian tables (device globals; rewritten every call) -------
__device__ float4 g_ga_s[NG];   // u, v, A, B    (conic pre-scaled by -0.5*log2e)
__device__ float4 g_gb_s[NG];   // C, opa_masked, cr, cg
__device__ float  g_cb_s[NG];

__device__ __forceinline__ float sigm(float x) { return 1.0f / (1.0f + __expf(-x)); }

// dtype discriminator (inputs proven f32 in R2; kept for safety):
// rot[0][1]==0.0 exactly -> 16-bit word #1 is 0x0000 for bf16, 0x3F7F for f32.
__device__ __forceinline__ bool detect_f32(const void* rot) {
    return ((const unsigned short*)rot)[1] != 0;
}
__device__ __forceinline__ float ld(const void* p, int idx, bool f32) {
    if (f32) return ((const float*)p)[idx];
    return __bfloat162float(((const __hip_bfloat16*)p)[idx]);
}

// ---------------------------------------------------------------------------
// Kernel 1: fused preprocess + stable rank sort.
// 128 blocks x 256 threads. Each block:
//   A) recomputes sort key r for ALL 2048 gaussians into LDS (cheap: ~25 flop)
//   B) ranks its 16 owned gaussians (16 lanes/gaussian, 128-key LDS slices)
//   C) threads 0..15 run the full conic preprocess for the 16 owned gaussians
//      and scatter straight into sorted position. No unsorted round-trip.
// ---------------------------------------------------------------------------
__global__ __launch_bounds__(256)
void prep_sort_kernel(const void* __restrict__ pos,
                      const void* __restrict__ rgb,
                      const void* __restrict__ opa,
                      const void* __restrict__ quat,
                      const void* __restrict__ scale,
                      const void* __restrict__ rot,
                      const void* __restrict__ tran)
{
    __shared__ float rs[NG];
    __shared__ int   srank[16];

    int tid = threadIdx.x;
    bool f32 = detect_f32(rot);

    float R[9], T3[3];
    #pragma unroll
    for (int k = 0; k < 9; k++) R[k] = ld(rot, k, f32);
    #pragma unroll
    for (int k = 0; k < 3; k++) T3[k] = ld(tran, k, f32);

    // ---- A: sort keys for all gaussians ----
    #pragma unroll
    for (int k = 0; k < NG / 256; k++) {
        int j = tid + k * 256;
        float p0 = ld(pos, j*3+0, f32), p1 = ld(pos, j*3+1, f32), p2 = ld(pos, j*3+2, f32);
        float x = R[0]*p0 + R[1]*p1 + R[2]*p2 + T3[0];
        float y = R[3]*p0 + R[4]*p1 + R[5]*p2 + T3[1];
        float z = R[6]*p0 + R[7]*p1 + R[8]*p2 + T3[2];
        rs[j] = sqrtf(x*x + y*y + z*z);
    }
    __syncthreads();

    // ---- B: rank the block's 16 gaussians ----
    int g      = blockIdx.x * 16 + (tid >> 4);
    int lane16 = tid & 15;
    float ri = rs[g];
    int rank = 0;
    int jbase = lane16 * CHUNK;
    #pragma unroll 4
    for (int jj = 0; jj < CHUNK; jj++) {
        int j = jbase + ((jj + 2 * lane16) & (CHUNK - 1));  // bank-spread
        float rj = rs[j];
        rank += (rj < ri) || (rj == ri && j < g);           // argsort-stable
    }
    #pragma unroll
    for (int d = 1; d < 16; d <<= 1) rank += __shfl_xor(rank, d);
    if (lane16 == 0) srank[tid >> 4] = rank;
    __syncthreads();

    // ---- C: full preprocess for the 16 owned gaussians, scatter sorted ----
    if (tid < 16) {
        int i = blockIdx.x * 16 + tid;
        int rk = srank[tid];

        float p0 = ld(pos, i*3+0, f32), p1 = ld(pos, i*3+1, f32), p2 = ld(pos, i*3+2, f32);
        float x = R[0]*p0 + R[1]*p1 + R[2]*p2 + T3[0];
        float y = R[3]*p0 + R[4]*p1 + R[5]*p2 + T3[1];
        float z = R[6]*p0 + R[7]*p1 + R[8]*p2 + T3[2];
        float iz = 1.0f / z;
        float u = x * iz, v = y * iz;

        float qw = ld(quat, i*4+0, f32), qx = ld(quat, i*4+1, f32);
        float qy = ld(quat, i*4+2, f32), qz = ld(quat, i*4+3, f32);
        float qn = 1.0f / sqrtf(qw*qw + qx*qx + qy*qy + qz*qz);
        qw *= qn; qx *= qn; qy *= qn; qz *= qn;
        float Rm[3][3];
        Rm[0][0] = 1.0f - 2.0f*(qy*qy + qz*qz);
        Rm[0][1] = 2.0f*(qx*qy - qw*qz);
        Rm[0][2] = 2.0f*(qx*qz + qw*qy);
        Rm[1][0] = 2.0f*(qx*qy + qw*qz);
        Rm[1][1] = 1.0f - 2.0f*(qx*qx + qz*qz);
        Rm[1][2] = 2.0f*(qy*qz - qw*qx);
        Rm[2][0] = 2.0f*(qx*qz - qw*qy);
        Rm[2][1] = 2.0f*(qy*qz + qw*qx);
        Rm[2][2] = 1.0f - 2.0f*(qx*qx + qy*qy);

        float s[3];
        #pragma unroll
        for (int k = 0; k < 3; k++) s[k] = fabsf(ld(scale, i*3+k, f32)) + 1e-4f;

        float RS[3][3];
        #pragma unroll
        for (int a = 0; a < 3; a++)
            #pragma unroll
            for (int b = 0; b < 3; b++) RS[a][b] = Rm[a][b] * s[b];
        float C3[3][3];
        #pragma unroll
        for (int a = 0; a < 3; a++)
            #pragma unroll
            for (int b = 0; b < 3; b++)
                C3[a][b] = RS[a][0]*RS[b][0] + RS[a][1]*RS[b][1] + RS[a][2]*RS[b][2];

        float nx = -x * iz * iz, ny = -y * iz * iz;
        float jw0[3], jw1[3];
        #pragma unroll
        for (int k = 0; k < 3; k++) {
            jw0[k] = iz * R[0*3+k] + nx * R[2*3+k];
            jw1[k] = iz * R[1*3+k] + ny * R[2*3+k];
        }
        float t0[3], t1[3];
        #pragma unroll
        for (int j = 0; j < 3; j++) {
            t0[j] = C3[j][0]*jw0[0] + C3[j][1]*jw0[1] + C3[j][2]*jw0[2];
            t1[j] = C3[j][0]*jw1[0] + C3[j][1]*jw1[1] + C3[j][2]*jw1[2];
        }
        float a = jw0[0]*t0[0] + jw0[1]*t0[1] + jw0[2]*t0[2] + GEPS;
        float b = jw0[0]*t1[0] + jw0[1]*t1[1] + jw0[2]*t1[2];
        float c = jw1[0]*t1[0] + jw1[1]*t1[1] + jw1[2]*t1[2] + GEPS;
        float idet = 1.0f / (a*c - b*b);
        float Af = -0.5f * LOG2E * (c * idet);
        float Bf = -LOG2E * (-b * idet);
        float Cf = -0.5f * LOG2E * (a * idet);

        float om = (z > NEARZ) ? sigm(ld(opa, i, f32)) : 0.0f;
        float cr = sigm(ld(rgb, i*3+0, f32));
        float cg = sigm(ld(rgb, i*3+1, f32));
        float cb = sigm(ld(rgb, i*3+2, f32));

        g_ga_s[rk] = make_float4(u, v, Af, Bf);
        g_gb_s[rk] = make_float4(Cf, om, cr, cg);
        g_cb_s[rk] = cb;
    }
}

// ---------------------------------------------------------------------------
// Kernel 2: rasterize. Block = 16 waves; wave w composites segment w for
// 64 pixels (pixel = lane); gaussian loads are wave-uniform addresses.
// Cross-segment ordered combine via LDS by wave 0.
// ---------------------------------------------------------------------------
__global__ __launch_bounds__(1024)
void raster_kernel(void* __restrict__ out, const void* __restrict__ rot)
{
    __shared__ float4 comb[SEG * 64];

    int tid  = threadIdx.x;
    int lane = tid & 63;
    int w    = __builtin_amdgcn_readfirstlane(tid >> 6);

    int pix = blockIdx.x * 64 + lane;
    int row = pix >> 7;
    int col = pix & 127;
    float pxf = (col - 63.5f) * (1.0f / 128.0f);
    float pyf = (row - 63.5f) * (1.0f / 128.0f);

    float T = 1.0f, Cr = 0.0f, Cg = 0.0f, Cb = 0.0f;
    int base = w * CHUNK;
    #pragma unroll 8
    for (int k = 0; k < CHUNK; k++) {
        float4 a4 = g_ga_s[base + k];   // wave-uniform address
        float4 b4 = g_gb_s[base + k];
        float  cb = g_cb_s[base + k];
        float dx = pxf - a4.x;
        float dy = pyf - a4.y;
        float p  = (a4.z * dx + a4.w * dy) * dx;   // A dx^2 + B dx dy (log2-dom)
        p = fmaf(b4.x * dy, dy, p);                // + C dy^2 ; NSD by construction
        float alpha = fminf(b4.y * __builtin_amdgcn_exp2f(p), 0.99f);
        float wgt = T * alpha;
        Cr = fmaf(wgt, b4.z, Cr);
        Cg = fmaf(wgt, b4.w, Cg);
        Cb = fmaf(wgt, cb, Cb);
        T -= wgt;                                  // T *= (1-alpha)
    }

    comb[w * 64 + lane] = make_float4(T, Cr, Cg, Cb);
    __syncthreads();

    if (tid < 64) {
        float Ta = 1.0f, Ra = 0.0f, Ga = 0.0f, Ba = 0.0f;
        #pragma unroll
        for (int s = 0; s < SEG; s++) {
            float4 c4 = comb[s * 64 + lane];
            Ra = fmaf(Ta, c4.y, Ra);
            Ga = fmaf(Ta, c4.z, Ga);
            Ba = fmaf(Ta, c4.w, Ba);
            Ta *= c4.x;
        }
        if (detect_f32(rot)) {
            float* o = (float*)out;
            o[pix*3 + 0] = Ra; o[pix*3 + 1] = Ga; o[pix*3 + 2] = Ba;
        } else {
            __hip_bfloat16* o = (__hip_bfloat16*)out;
            o[pix*3 + 0] = __float2bfloat16(Ra);
            o[pix*3 + 1] = __float2bfloat16(Ga);
            o[pix*3 + 2] = __float2bfloat16(Ba);
        }
    }
}

// ---------------------------------------------------------------------------
extern "C" void kernel_launch(void* const* d_in, const int* in_sizes, int n_in,
                              void* d_out, int out_size, void* d_ws, size_t ws_size,
                              hipStream_t stream)
{
    const void* pos   = d_in[0];
    const void* rgb   = d_in[1];
    const void* opa   = d_in[2];
    const void* quat  = d_in[3];
    const void* scale = d_in[4];
    const void* rot   = d_in[5];
    const void* tran  = d_in[6];

    prep_sort_kernel<<<NG/16, 256, 0, stream>>>(pos, rgb, opa, quat, scale, rot, tran);
    raster_kernel<<<NPIX/64, 1024, 0, stream>>>(d_out, rot);
}

// Round 5
// 90.263 us; speedup vs baseline: 2.7637x; 1.0768x over previous
//
#include <hip/hip_runtime.h>
#include <hip/hip_bf16.h>

#define NG     2048
#define HW     128
#define NPIX   (HW*HW)
#define SEG    16
#define CHUNK  (NG/SEG)   // 128
#define NEARZ  0.3f
#define GEPS   1e-4f
#define LOG2E  1.4426950408889634f

// ---- sorted gaussian tables (device globals; rewritten every call) -------
__device__ float4   g_ga_s[NG];  // u, v, A, B   (conic pre-scaled by -0.5*log2e)
__device__ float4   g_gb_s[NG];  // C, opa_masked, cr, cg
__device__ float    g_cb_s[NG];
__device__ unsigned g_bb_s[NG];  // packed AABB: ymin<<24|ymax<<16|xmin<<8|xmax

__device__ __forceinline__ float sigm(float x) { return 1.0f / (1.0f + __expf(-x)); }

// dtype discriminator (inputs proven f32 in R2; kept for safety):
// rot[0][1]==0.0 exactly -> 16-bit word #1 is 0x0000 for bf16, 0x3F7F for f32.
__device__ __forceinline__ bool detect_f32(const void* rot) {
    return ((const unsigned short*)rot)[1] != 0;
}
__device__ __forceinline__ float ld(const void* p, int idx, bool f32) {
    if (f32) return ((const float*)p)[idx];
    return __bfloat162float(((const __hip_bfloat16*)p)[idx]);
}

// ---------------------------------------------------------------------------
// Kernel 1: fused preprocess + stable rank sort + AABB computation.
// 128 blocks x 256 threads (16 gaussians/block).
// ---------------------------------------------------------------------------
__global__ __launch_bounds__(256)
void prep_sort_kernel(const void* __restrict__ pos,
                      const void* __restrict__ rgb,
                      const void* __restrict__ opa,
                      const void* __restrict__ quat,
                      const void* __restrict__ scale,
                      const void* __restrict__ rot,
                      const void* __restrict__ tran)
{
    __shared__ float rs[NG];
    __shared__ int   srank[16];

    int tid = threadIdx.x;
    bool f32 = detect_f32(rot);

    float R[9], T3[3];
    #pragma unroll
    for (int k = 0; k < 9; k++) R[k] = ld(rot, k, f32);
    #pragma unroll
    for (int k = 0; k < 3; k++) T3[k] = ld(tran, k, f32);

    // ---- A: sort keys for all gaussians ----
    #pragma unroll
    for (int k = 0; k < NG / 256; k++) {
        int j = tid + k * 256;
        float p0 = ld(pos, j*3+0, f32), p1 = ld(pos, j*3+1, f32), p2 = ld(pos, j*3+2, f32);
        float x = R[0]*p0 + R[1]*p1 + R[2]*p2 + T3[0];
        float y = R[3]*p0 + R[4]*p1 + R[5]*p2 + T3[1];
        float z = R[6]*p0 + R[7]*p1 + R[8]*p2 + T3[2];
        rs[j] = sqrtf(x*x + y*y + z*z);
    }
    __syncthreads();

    // ---- B: rank the block's 16 gaussians (16 lanes each) ----
    int g      = blockIdx.x * 16 + (tid >> 4);
    int lane16 = tid & 15;
    float ri = rs[g];
    int rank = 0;
    int jbase = lane16 * CHUNK;
    #pragma unroll 4
    for (int jj = 0; jj < CHUNK; jj++) {
        int j = jbase + ((jj + 2 * lane16) & (CHUNK - 1));
        float rj = rs[j];
        rank += (rj < ri) || (rj == ri && j < g);           // argsort-stable
    }
    #pragma unroll
    for (int d = 1; d < 16; d <<= 1) rank += __shfl_xor(rank, d);
    if (lane16 == 0) srank[tid >> 4] = rank;
    __syncthreads();

    // ---- C: full preprocess for 16 owned gaussians, scatter sorted ----
    if (tid < 16) {
        int i  = blockIdx.x * 16 + tid;
        int rk = srank[tid];

        float p0 = ld(pos, i*3+0, f32), p1 = ld(pos, i*3+1, f32), p2 = ld(pos, i*3+2, f32);
        float x = R[0]*p0 + R[1]*p1 + R[2]*p2 + T3[0];
        float y = R[3]*p0 + R[4]*p1 + R[5]*p2 + T3[1];
        float z = R[6]*p0 + R[7]*p1 + R[8]*p2 + T3[2];
        float iz = 1.0f / z;
        float u = x * iz, v = y * iz;

        float qw = ld(quat, i*4+0, f32), qx = ld(quat, i*4+1, f32);
        float qy = ld(quat, i*4+2, f32), qz = ld(quat, i*4+3, f32);
        float qn = 1.0f / sqrtf(qw*qw + qx*qx + qy*qy + qz*qz);
        qw *= qn; qx *= qn; qy *= qn; qz *= qn;
        float Rm[3][3];
        Rm[0][0] = 1.0f - 2.0f*(qy*qy + qz*qz);
        Rm[0][1] = 2.0f*(qx*qy - qw*qz);
        Rm[0][2] = 2.0f*(qx*qz + qw*qy);
        Rm[1][0] = 2.0f*(qx*qy + qw*qz);
        Rm[1][1] = 1.0f - 2.0f*(qx*qx + qz*qz);
        Rm[1][2] = 2.0f*(qy*qz - qw*qx);
        Rm[2][0] = 2.0f*(qx*qz - qw*qy);
        Rm[2][1] = 2.0f*(qy*qz + qw*qx);
        Rm[2][2] = 1.0f - 2.0f*(qx*qx + qy*qy);

        float s[3];
        #pragma unroll
        for (int k = 0; k < 3; k++) s[k] = fabsf(ld(scale, i*3+k, f32)) + 1e-4f;

        float RS[3][3];
        #pragma unroll
        for (int a = 0; a < 3; a++)
            #pragma unroll
            for (int b = 0; b < 3; b++) RS[a][b] = Rm[a][b] * s[b];
        float C3[3][3];
        #pragma unroll
        for (int a = 0; a < 3; a++)
            #pragma unroll
            for (int b = 0; b < 3; b++)
                C3[a][b] = RS[a][0]*RS[b][0] + RS[a][1]*RS[b][1] + RS[a][2]*RS[b][2];

        float nx = -x * iz * iz, ny = -y * iz * iz;
        float jw0[3], jw1[3];
        #pragma unroll
        for (int k = 0; k < 3; k++) {
            jw0[k] = iz * R[0*3+k] + nx * R[2*3+k];
            jw1[k] = iz * R[1*3+k] + ny * R[2*3+k];
        }
        float t0[3], t1[3];
        #pragma unroll
        for (int j = 0; j < 3; j++) {
            t0[j] = C3[j][0]*jw0[0] + C3[j][1]*jw0[1] + C3[j][2]*jw0[2];
            t1[j] = C3[j][0]*jw1[0] + C3[j][1]*jw1[1] + C3[j][2]*jw1[2];
        }
        float a = jw0[0]*t0[0] + jw0[1]*t0[1] + jw0[2]*t0[2] + GEPS;
        float b = jw0[0]*t1[0] + jw0[1]*t1[1] + jw0[2]*t1[2];
        float c = jw1[0]*t1[0] + jw1[1]*t1[1] + jw1[2]*t1[2] + GEPS;
        float det  = a*c - b*b;
        float idet = 1.0f / det;
        float Af = -0.5f * LOG2E * (c * idet);
        float Bf = -LOG2E * (-b * idet);
        float Cf = -0.5f * LOG2E * (a * idet);

        float om = (z > NEARZ) ? sigm(ld(opa, i, f32)) : 0.0f;
        float cr = sigm(ld(rgb, i*3+0, f32));
        float cg = sigm(ld(rgb, i*3+1, f32));
        float cb = sigm(ld(rgb, i*3+2, f32));

        // conservative AABB: |d| > 6.5*sqrt(lam_max)  =>  alpha < e^-21
        float mid = 0.5f * (a + c);
        float lam = mid + sqrtf(fmaxf(mid*mid - det, 0.0f));
        float rad = 6.5f * sqrtf(lam) * 128.0f;     // pixels
        float u_px = u * 128.0f + 63.5f;
        float v_px = v * 128.0f + 63.5f;
        unsigned bb = 0xFF00FF00u;                  // "never hits" sentinel
        if (om > 0.0f) {
            int ymn = (int)ceilf (v_px - rad);
            int ymx = (int)floorf(v_px + rad);
            int xmn = (int)ceilf (u_px - rad);
            int xmx = (int)floorf(u_px + rad);
            if (ymx >= 0 && ymn <= 127 && xmx >= 0 && xmn <= 127) {
                ymn = max(ymn, 0); ymx = min(ymx, 127);
                xmn = max(xmn, 0); xmx = min(xmx, 127);
                bb = (unsigned)((ymn << 24) | (ymx << 16) | (xmn << 8) | xmx);
            }
        }

        g_ga_s[rk] = make_float4(u, v, Af, Bf);
        g_gb_s[rk] = make_float4(Cf, om, cr, cg);
        g_cb_s[rk] = cb;
        g_bb_s[rk] = bb;
    }
}

// ---------------------------------------------------------------------------
// Kernel 2: rasterize with ballot culling.
// 256 blocks x 1024 threads. Block = 64-px row strip (row uniform!).
// Wave w owns sorted segment w; 64 lanes vector-test 64 AABBs, ballot,
// then ctz-walk the survivors (ascending => order preserved).
// ---------------------------------------------------------------------------
__global__ __launch_bounds__(1024)
void raster_kernel(void* __restrict__ out, const void* __restrict__ rot)
{
    __shared__ float4 comb[SEG * 64];

    int tid  = threadIdx.x;
    int lane = tid & 63;
    int w    = __builtin_amdgcn_readfirstlane(tid >> 6);

    int pix = blockIdx.x * 64 + lane;
    int row = blockIdx.x >> 1;          // uniform per block
    int x0  = (blockIdx.x & 1) * 64;    // uniform strip start
    int x1  = x0 + 63;
    int col = x0 + lane;
    float pxf = (col - 63.5f) * (1.0f / 128.0f);
    float pyf = (row - 63.5f) * (1.0f / 128.0f);

    float T = 1.0f, Cr = 0.0f, Cg = 0.0f, Cb = 0.0f;
    int base = w * CHUNK;

    #pragma unroll
    for (int c = 0; c < CHUNK / 64; c++) {          // 2 chunks of 64
        int cbase = base + c * 64;
        unsigned bb = g_bb_s[cbase + lane];          // coalesced vector load
        int ymn =  bb >> 24;
        int ymx = (bb >> 16) & 255;
        int xmn = (bb >>  8) & 255;
        int xmx =  bb        & 255;
        bool hit = (row >= ymn) & (row <= ymx) & (x1 >= xmn) & (x0 <= xmx);
        unsigned long long m = __ballot(hit);
        while (m) {
            int kk = __builtin_ctzll(m);
            m &= m - 1;
            int idx = cbase + kk;                    // scalar (uniform) index
            float4 a4 = g_ga_s[idx];
            float4 b4 = g_gb_s[idx];
            float  cc = g_cb_s[idx];
            float dx = pxf - a4.x;
            float dy = pyf - a4.y;
            float p  = (a4.z * dx + a4.w * dy) * dx;
            p = fmaf(b4.x * dy, dy, p);              // log2-domain, NSD
            float alpha = fminf(b4.y * __builtin_amdgcn_exp2f(p), 0.99f);
            float wgt = T * alpha;
            Cr = fmaf(wgt, b4.z, Cr);
            Cg = fmaf(wgt, b4.w, Cg);
            Cb = fmaf(wgt, cc, Cb);
            T -= wgt;                                // T *= (1-alpha)
        }
    }

    comb[w * 64 + lane] = make_float4(T, Cr, Cg, Cb);
    __syncthreads();

    if (tid < 64) {
        float Ta = 1.0f, Ra = 0.0f, Ga = 0.0f, Ba = 0.0f;
        #pragma unroll
        for (int s = 0; s < SEG; s++) {
            float4 c4 = comb[s * 64 + lane];
            Ra = fmaf(Ta, c4.y, Ra);
            Ga = fmaf(Ta, c4.z, Ga);
            Ba = fmaf(Ta, c4.w, Ba);
            Ta *= c4.x;
        }
        if (detect_f32(rot)) {
            float* o = (float*)out;
            o[pix*3 + 0] = Ra; o[pix*3 + 1] = Ga; o[pix*3 + 2] = Ba;
        } else {
            __hip_bfloat16* o = (__hip_bfloat16*)out;
            o[pix*3 + 0] = __float2bfloat16(Ra);
            o[pix*3 + 1] = __float2bfloat16(Ga);
            o[pix*3 + 2] = __float2bfloat16(Ba);
        }
    }
}

// ---------------------------------------------------------------------------
extern "C" void kernel_launch(void* const* d_in, const int* in_sizes, int n_in,
                              void* d_out, int out_size, void* d_ws, size_t ws_size,
                              hipStream_t stream)
{
    const void* pos   = d_in[0];
    const void* rgb   = d_in[1];
    const void* opa   = d_in[2];
    const void* quat  = d_in[3];
    const void* scale = d_in[4];
    const void* rot   = d_in[5];
    const void* tran  = d_in[6];

    prep_sort_kernel<<<NG/16, 256, 0, stream>>>(pos, rgb, opa, quat, scale, rot, tran);
    raster_kernel<<<NPIX/64, 1024, 0, stream>>>(d_out, rot);
}